// Round 4
// baseline (49801.474 us; speedup 1.0000x reference)
//
#include <hip/hip_runtime.h>

#define UNITS   2048
#define IN_DIM  128
#define T_STEPS 4096
#define NBLK    64
#define TPB     1024
#define BROWS   32    // rows per block
#define GROWS   8     // rows per thread-group
#define KCH     8     // contiguous cols per thread

typedef unsigned int u32;
typedef u32 u32x4 __attribute__((ext_vector_type(4)));
typedef u32 u32x2 __attribute__((ext_vector_type(2)));

// Reset pair tags so stale tags from a previous graph replay can never match.
__global__ void esn_init(u32x2* __restrict__ buf) {
    int i = blockIdx.x * blockDim.x + threadIdx.x;
    if (i < 2 * UNITS) { u32x2 z; z[0] = 0u; z[1] = 0u; buf[i] = z; }
}

template <int CTRL>
__device__ __forceinline__ float dpp_add(float x) {
    int y = __builtin_amdgcn_update_dpp(0, __float_as_int(x), CTRL, 0xF, 0xF, true);
    return x + __int_as_float(y);
}

__global__ void __launch_bounds__(TPB, 4) esn_step(
    const float* __restrict__ inp,   // [4096][128]
    const float* __restrict__ s0,    // [2048]
    const float* __restrict__ W,     // [2048][2048] row-major
    const float* __restrict__ Win,   // [2048][128]
    float* __restrict__ out,         // [4096*2048 + 2048]
    u32x2* __restrict__ buf)         // [2][2048] (value, step-tag) pairs
{
    const int b    = blockIdx.x;
    const int tid  = threadIdx.x;
    const int c    = tid & 255;      // col chunk id: this thread's cols are 8c..8c+7
    const int g    = tid >> 8;       // row group 0..3
    const int lane = tid & 63;
    const int wv   = tid >> 6;       // wave 0..15

    // ---- W fragment in registers: rows row0..row0+7, cols 8c..8c+7 (64 regs) ----
    const int row0 = b * BROWS + g * GROWS;
    float w[GROWS][KCH];
    #pragma unroll
    for (int r = 0; r < GROWS; ++r) {
        const float* wp = W + (size_t)(row0 + r) * UNITS + c * KCH;
        float4 lo = *(const float4*)(wp);
        float4 hi = *(const float4*)(wp + 4);
        w[r][0] = lo.x; w[r][1] = lo.y; w[r][2] = lo.z; w[r][3] = lo.w;
        w[r][4] = hi.x; w[r][5] = hi.y; w[r][6] = hi.z; w[r][7] = hi.w;
    }
    // ---- Win fragment: thread with c<128 owns input col c for its 8 rows ----
    float winv[GROWS];
    #pragma unroll
    for (int r = 0; r < GROWS; ++r) winv[r] = 0.f;
    if (c < IN_DIM) {
        #pragma unroll
        for (int r = 0; r < GROWS; ++r)
            winv[r] = Win[(size_t)(row0 + r) * IN_DIM + c];
    }

    // finalizer lanes: lanes 0-7 of waves 0,4,8,12 own rows row0..row0+7
    float s_old = ((tid & 255) < GROWS) ? s0[row0 + (tid & 7)] : 0.f;

    // preload sv = s_0 for step 0 (no comm needed)
    float sv[KCH];
    {
        const float* sp = s0 + c * KCH;
        float4 lo = *(const float4*)(sp);
        float4 hi = *(const float4*)(sp + 4);
        sv[0] = lo.x; sv[1] = lo.y; sv[2] = lo.z; sv[3] = lo.w;
        sv[4] = hi.x; sv[5] = hi.y; sv[6] = hi.z; sv[7] = hi.w;
    }

    __shared__ float red[2][16][4][GROWS];   // per-wave, per-16-lane partials
    __shared__ u32 cnt_red[2][4];            // monotone per-group wave counters

    if (tid < 8) cnt_red[tid >> 2][tid & 3] = 0u;
    __syncthreads();   // one-time only

    for (int t = 0; t < T_STEPS; ++t) {
        const int par   = t & 1;
        const u32 epoch = (u32)(t >> 1) + 1u;

        // input drive for step t (issued before the poll; absorbed by its waitcnt)
        float u = 0.f;
        if (c < IN_DIM) u = inp[(size_t)t * IN_DIM + c];

        // ---- poll own 8 (val,tag) pairs (64B) straight into FMA operands ----
        if (t > 0) {
            const u32x2* pp = buf + par * UNITS + c * KCH;
            const u32 tag = (u32)t;
            u32x4 A, B, C, D;
            while (true) {
                asm volatile(
                    "global_load_dwordx4 %0, %4, off sc0 sc1\n\t"
                    "global_load_dwordx4 %1, %4, off offset:16 sc0 sc1\n\t"
                    "global_load_dwordx4 %2, %4, off offset:32 sc0 sc1\n\t"
                    "global_load_dwordx4 %3, %4, off offset:48 sc0 sc1\n\t"
                    "s_waitcnt vmcnt(0)"
                    : "=v"(A), "=v"(B), "=v"(C), "=v"(D)
                    : "v"(pp)
                    : "memory");
                bool ok = (A[1] == tag) & (A[3] == tag) & (B[1] == tag) & (B[3] == tag)
                        & (C[1] == tag) & (C[3] == tag) & (D[1] == tag) & (D[3] == tag);
                if (ok) break;
            }
            sv[0] = __uint_as_float(A[0]); sv[1] = __uint_as_float(A[2]);
            sv[2] = __uint_as_float(B[0]); sv[3] = __uint_as_float(B[2]);
            sv[4] = __uint_as_float(C[0]); sv[5] = __uint_as_float(C[2]);
            sv[6] = __uint_as_float(D[0]); sv[7] = __uint_as_float(D[2]);
        }

        // ---- partial matvec: 64 FMAs over contiguous cols ----
        float acc[GROWS];
        #pragma unroll
        for (int r = 0; r < GROWS; ++r) {
            float a = 0.f;
            #pragma unroll
            for (int k = 0; k < KCH; ++k) a = fmaf(w[r][k], sv[k], a);
            acc[r] = a;
        }
        if (c < IN_DIM) {
            #pragma unroll
            for (int r = 0; r < GROWS; ++r) acc[r] = fmaf(winv[r], u, acc[r]);
        }

        // ---- 16-lane reduce via VALU DPP (sums 128 contiguous cols) ----
        #pragma unroll
        for (int r = 0; r < GROWS; ++r) {
            acc[r] = dpp_add<0xB1>(acc[r]);    // quad_perm xor1
            acc[r] = dpp_add<0x4E>(acc[r]);    // quad_perm xor2
            acc[r] = dpp_add<0x141>(acc[r]);   // row_half_mirror (+other quad)
            acc[r] = dpp_add<0x140>(acc[r]);   // row_mirror (+other 8)
        }
        if ((lane & 15) < 8) {
            float v = acc[0];                  // static select acc[lane&7]
            #pragma unroll
            for (int r = 1; r < GROWS; ++r) v = ((lane & 7) == r) ? acc[r] : v;
            red[par][wv][lane >> 4][lane & 7] = v;
        }
        if (lane == 0)
            __hip_atomic_fetch_add(&cnt_red[par][g], 1u, __ATOMIC_RELEASE,
                                   __HIP_MEMORY_SCOPE_WORKGROUP);

        // ---- finalize: lanes 0-7 of wave 4g combine own group's 16 partials ----
        if ((tid & 255) < GROWS) {
            while (__hip_atomic_load(&cnt_red[par][g], __ATOMIC_ACQUIRE,
                                     __HIP_MEMORY_SCOPE_WORKGROUP) < 4u * epoch) {}
            const int rr = tid & 7;
            float pre = 0.f;
            #pragma unroll
            for (int q = 0; q < 4; ++q)
                #pragma unroll
                for (int h = 0; h < 4; ++h)
                    pre += red[par][4 * g + q][h][rr];
            float e  = __expf(2.0f * pre);
            float th = 1.0f - 2.0f / (e + 1.0f);
            float sn = 0.9f * s_old + 0.1f * th;
            s_old = sn;
            const int j = row0 + rr;
            out[(size_t)t * UNITS + j] = sn;
            if (t == T_STEPS - 1) {
                out[(size_t)T_STEPS * UNITS + j] = sn;
            } else {
                u32x2 vt; vt[0] = __float_as_uint(sn); vt[1] = (u32)(t + 1);
                u32x2* ps = buf + ((t + 1) & 1) * UNITS + j;
                asm volatile("global_store_dwordx2 %0, %1, off sc0 sc1"
                             :: "v"(ps), "v"(vt) : "memory");
            }
        }
    }
}

extern "C" void kernel_launch(void* const* d_in, const int* in_sizes, int n_in,
                              void* d_out, int out_size, void* d_ws, size_t ws_size,
                              hipStream_t stream) {
    const float* inp = (const float*)d_in[0];   // input_sequence [4096,128]
    const float* s0  = (const float*)d_in[1];   // initial_state  [1,2048]
    const float* W   = (const float*)d_in[2];   // W   [2048,2048]
    const float* Win = (const float*)d_in[3];   // Win [2048,128]
    float* out = (float*)d_out;
    u32x2* buf = (u32x2*)d_ws;                  // 2*2048*8 = 32 KiB scratch

    esn_init<<<dim3(16), dim3(256), 0, stream>>>(buf);

    void* args[6];
    args[0] = (void*)&inp; args[1] = (void*)&s0;  args[2] = (void*)&W;
    args[3] = (void*)&Win; args[4] = (void*)&out; args[5] = (void*)&buf;
    hipLaunchCooperativeKernel((void*)esn_step, dim3(NBLK), dim3(TPB), args, 0, stream);
}

// Round 5
// 12037.215 us; speedup vs baseline: 4.1373x; 4.1373x over previous
//
#include <hip/hip_runtime.h>

#define UNITS   2048
#define IN_DIM  128
#define T_STEPS 4096
#define NBLK    64
#define TPB     1024
#define BROWS   32    // rows per block
#define GROWS   8     // rows per thread-group
#define KCH     8     // cols per thread
#define CSTR    256   // col stride between a thread's cols

typedef unsigned int u32;
typedef u32 u32x4 __attribute__((ext_vector_type(4)));
typedef u32 u32x2 __attribute__((ext_vector_type(2)));

// Reset pair tags so stale tags from a previous graph replay can never match.
__global__ void esn_init(u32x2* __restrict__ buf) {
    int i = blockIdx.x * blockDim.x + threadIdx.x;
    if (i < 2 * UNITS) { u32x2 z; z[0] = 0u; z[1] = 0u; buf[i] = z; }
}

template <int CTRL>
__device__ __forceinline__ float dpp_add(float x) {
    int y = __builtin_amdgcn_update_dpp(0, __float_as_int(x), CTRL, 0xF, 0xF, true);
    return x + __int_as_float(y);
}

__global__ void __launch_bounds__(TPB, 1) esn_step(
    const float* __restrict__ inp,   // [4096][128]
    const float* __restrict__ s0,    // [2048]
    const float* __restrict__ W,     // [2048][2048] row-major
    const float* __restrict__ Win,   // [2048][128]
    float* __restrict__ out,         // [4096*2048 + 2048]
    u32x2* __restrict__ buf)         // [2][2048] (value, step-tag) pairs
{
    const int b    = blockIdx.x;
    const int tid  = threadIdx.x;
    const int c    = tid & 255;      // col id: this thread's cols are c + 256*j
    const int g    = tid >> 8;       // row group 0..3
    const int lane = tid & 63;
    const int wv   = tid >> 6;       // wave 0..15

    // ---- W fragment: rows row0..row0+7, cols c+256*j — FORCED register-resident ----
    const int row0 = b * BROWS + g * GROWS;
    float w[GROWS][KCH];
    #pragma unroll
    for (int r = 0; r < GROWS; ++r) {
        const float* wp = W + (size_t)(row0 + r) * UNITS + c;
        #pragma unroll
        for (int j = 0; j < KCH; ++j) w[r][j] = wp[j * CSTR];
    }
    #pragma unroll
    for (int r = 0; r < GROWS; ++r)
        #pragma unroll
        for (int j = 0; j < KCH; ++j)
            asm volatile("" : "+v"(w[r][j]));   // opaque def: no re-load from global

    float winv[GROWS];
    #pragma unroll
    for (int r = 0; r < GROWS; ++r) winv[r] = 0.f;
    if (c < IN_DIM) {
        #pragma unroll
        for (int r = 0; r < GROWS; ++r)
            winv[r] = Win[(size_t)(row0 + r) * IN_DIM + c];
    }
    #pragma unroll
    for (int r = 0; r < GROWS; ++r) asm volatile("" : "+v"(winv[r]));

    // ---- finalizer role: lanes 0-7 of waves 4,8,12,15 own groups 0,1,2,3 ----
    int fg = -1;
    if (lane < 8) {
        if (wv == 4) fg = 0; else if (wv == 8) fg = 1;
        else if (wv == 12) fg = 2; else if (wv == 15) fg = 3;
    }
    float s_old = (fg >= 0) ? s0[b * BROWS + fg * GROWS + lane] : 0.f;

    __shared__ float sv_lds[2][UNITS];        // parity-buffered state vector
    __shared__ float red[2][16][4][GROWS];    // per-wave, per-16-lane partials
    __shared__ u32 cnt_sv[2];                 // monotone poller-deposit counters
    __shared__ u32 cnt_red[2][4];             // monotone per-group wave counters

    // ---- pre-loop: local deposit of s_0 (no comm needed for step 0) ----
    if (tid < 256) {
        float4 a  = *(const float4*)(s0 + tid * 8);
        float4 bb = *(const float4*)(s0 + tid * 8 + 4);
        *(float4*)&sv_lds[0][tid * 8]     = a;
        *(float4*)&sv_lds[0][tid * 8 + 4] = bb;
    }
    if (tid == 0) { cnt_sv[0] = 4u; cnt_sv[1] = 0u; }
    if (tid < 8)  cnt_red[tid >> 2][tid & 3] = 0u;
    __syncthreads();   // one-time only

    for (int t = 0; t < T_STEPS; ++t) {
        const int par   = t & 1;
        const u32 epoch = (u32)(t >> 1) + 1u;

        // input drive for step t
        float u = 0.f;
        if (c < IN_DIM) u = inp[(size_t)t * IN_DIM + c];

        // ---- wait for sv[par] = s_t (pollers spin tight; others back off) ----
        if (wv >= 4) {
            while (__hip_atomic_load(&cnt_sv[par], __ATOMIC_ACQUIRE,
                                     __HIP_MEMORY_SCOPE_WORKGROUP) < 4u * epoch)
                __builtin_amdgcn_s_sleep(1);
        } else {
            while (__hip_atomic_load(&cnt_sv[par], __ATOMIC_ACQUIRE,
                                     __HIP_MEMORY_SCOPE_WORKGROUP) < 4u * epoch) {}
        }

        // ---- operands from LDS (lane-consecutive: conflict-free) ----
        float sv[KCH];
        #pragma unroll
        for (int j = 0; j < KCH; ++j) sv[j] = sv_lds[par][c + j * CSTR];

        // ---- partial matvec: 64 FMAs ----
        float acc[GROWS];
        #pragma unroll
        for (int r = 0; r < GROWS; ++r) {
            float a = 0.f;
            #pragma unroll
            for (int k = 0; k < KCH; ++k) a = fmaf(w[r][k], sv[k], a);
            acc[r] = a;
        }
        if (c < IN_DIM) {
            #pragma unroll
            for (int r = 0; r < GROWS; ++r) acc[r] = fmaf(winv[r], u, acc[r]);
        }

        // ---- 16-lane reduce via VALU DPP ----
        #pragma unroll
        for (int r = 0; r < GROWS; ++r) {
            acc[r] = dpp_add<0xB1>(acc[r]);    // quad_perm xor1
            acc[r] = dpp_add<0x4E>(acc[r]);    // quad_perm xor2
            acc[r] = dpp_add<0x141>(acc[r]);   // row_half_mirror
            acc[r] = dpp_add<0x140>(acc[r]);   // row_mirror
        }
        if ((lane & 15) < 8) {
            float v = acc[0];                  // static select acc[lane&7]
            #pragma unroll
            for (int r = 1; r < GROWS; ++r) v = ((lane & 7) == r) ? acc[r] : v;
            red[par][wv][lane >> 4][lane & 7] = v;
        }
        if (lane == 0)
            __hip_atomic_fetch_add(&cnt_red[par][g], 1u, __ATOMIC_RELEASE,
                                   __HIP_MEMORY_SCOPE_WORKGROUP);

        // ---- finalize: non-poller waves combine own group's 16 partials ----
        if (fg >= 0) {
            while (__hip_atomic_load(&cnt_red[par][fg], __ATOMIC_ACQUIRE,
                                     __HIP_MEMORY_SCOPE_WORKGROUP) < 4u * epoch) {}
            float pre = 0.f;
            #pragma unroll
            for (int q = 0; q < 4; ++q)
                #pragma unroll
                for (int h = 0; h < 4; ++h)
                    pre += red[par][4 * fg + q][h][lane];
            float e  = __expf(2.0f * pre);
            float th = 1.0f - 2.0f / (e + 1.0f);
            float sn = 0.9f * s_old + 0.1f * th;
            s_old = sn;
            const int j = b * BROWS + fg * GROWS + lane;
            out[(size_t)t * UNITS + j] = sn;
            if (t == T_STEPS - 1) {
                out[(size_t)T_STEPS * UNITS + j] = sn;
            } else {
                u32x2 vt; vt[0] = __float_as_uint(sn); vt[1] = (u32)(t + 1);
                u32x2* ps = buf + ((t + 1) & 1) * UNITS + j;
                asm volatile("global_store_dwordx2 %0, %1, off sc0 sc1"
                             :: "v"(ps), "v"(vt) : "memory");
            }
        }

        // ---- pollers gather s_{t+1}: 4B tag probe, then 64B fetch+validate ----
        if (wv < 4 && t < T_STEPS - 1) {
            const int pnx = (t + 1) & 1;
            const u32 tag = (u32)(t + 1);
            const u32x2* pp = buf + pnx * UNITS + tid * KCH;
            const u32* tp = (const u32*)pp + 1;        // tag of first pair in line
            u32 tg;
            do {
                asm volatile("global_load_dword %0, %1, off sc0 sc1\n\t"
                             "s_waitcnt vmcnt(0)"
                             : "=v"(tg) : "v"(tp) : "memory");
            } while (tg != tag);
            u32x4 A, B, C, D;
            while (true) {
                asm volatile(
                    "global_load_dwordx4 %0, %4, off sc0 sc1\n\t"
                    "global_load_dwordx4 %1, %4, off offset:16 sc0 sc1\n\t"
                    "global_load_dwordx4 %2, %4, off offset:32 sc0 sc1\n\t"
                    "global_load_dwordx4 %3, %4, off offset:48 sc0 sc1\n\t"
                    "s_waitcnt vmcnt(0)"
                    : "=v"(A), "=v"(B), "=v"(C), "=v"(D)
                    : "v"(pp)
                    : "memory");
                bool ok = (A[1] == tag) & (A[3] == tag) & (B[1] == tag) & (B[3] == tag)
                        & (C[1] == tag) & (C[3] == tag) & (D[1] == tag) & (D[3] == tag);
                if (ok) break;
            }
            float4 v0, v1;
            v0.x = __uint_as_float(A[0]); v0.y = __uint_as_float(A[2]);
            v0.z = __uint_as_float(B[0]); v0.w = __uint_as_float(B[2]);
            v1.x = __uint_as_float(C[0]); v1.y = __uint_as_float(C[2]);
            v1.z = __uint_as_float(D[0]); v1.w = __uint_as_float(D[2]);
            float4* dst = (float4*)&sv_lds[pnx][tid * KCH];
            dst[0] = v0; dst[1] = v1;
            if (lane == 0)
                __hip_atomic_fetch_add(&cnt_sv[pnx], 1u, __ATOMIC_RELEASE,
                                       __HIP_MEMORY_SCOPE_WORKGROUP);
        }
    }
}

extern "C" void kernel_launch(void* const* d_in, const int* in_sizes, int n_in,
                              void* d_out, int out_size, void* d_ws, size_t ws_size,
                              hipStream_t stream) {
    const float* inp = (const float*)d_in[0];   // input_sequence [4096,128]
    const float* s0  = (const float*)d_in[1];   // initial_state  [1,2048]
    const float* W   = (const float*)d_in[2];   // W   [2048,2048]
    const float* Win = (const float*)d_in[3];   // Win [2048,128]
    float* out = (float*)d_out;
    u32x2* buf = (u32x2*)d_ws;                  // 2*2048*8 = 32 KiB scratch

    esn_init<<<dim3(16), dim3(256), 0, stream>>>(buf);

    void* args[6];
    args[0] = (void*)&inp; args[1] = (void*)&s0;  args[2] = (void*)&W;
    args[3] = (void*)&Win; args[4] = (void*)&out; args[5] = (void*)&buf;
    hipLaunchCooperativeKernel((void*)esn_step, dim3(NBLK), dim3(TPB), args, 0, stream);
}

// Round 6
// 10440.172 us; speedup vs baseline: 4.7702x; 1.1530x over previous
//
#include <hip/hip_runtime.h>

#define UNITS   2048
#define IN_DIM  128
#define T_STEPS 4096
#define NBLK    64
#define TPB     1024
#define BROWS   32    // rows per block
#define GROWS   8     // rows per thread-group
#define KCH     8     // cols per thread
#define CSTR    256   // col stride between a thread's cols

typedef unsigned int u32;
typedef u32 u32x4 __attribute__((ext_vector_type(4)));
typedef u32 u32x2 __attribute__((ext_vector_type(2)));

// Reset pair tags so stale tags from a previous graph replay can never match.
// Tag 0 is never polled (first poll looks for tag 1).
__global__ void esn_init(u32x2* __restrict__ buf) {
    int i = blockIdx.x * blockDim.x + threadIdx.x;
    if (i < 2 * UNITS) { u32x2 z; z[0] = 0u; z[1] = 0u; buf[i] = z; }
}

template <int CTRL>
__device__ __forceinline__ float dpp_add(float x) {
    int y = __builtin_amdgcn_update_dpp(0, __float_as_int(x), CTRL, 0xF, 0xF, true);
    return x + __int_as_float(y);
}

__global__ void __launch_bounds__(TPB, 4)
__attribute__((amdgpu_waves_per_eu(4, 4)))
esn_step(
    const float* __restrict__ inp,   // [4096][128]
    const float* __restrict__ s0,    // [2048]
    const float* __restrict__ W,     // [2048][2048] row-major
    const float* __restrict__ Win,   // [2048][128]
    float* __restrict__ out,         // [4096*2048 + 2048]
    u32x2* __restrict__ buf)         // [2][2048] (value, step-tag) pairs
{
    const int b    = blockIdx.x;
    const int tid  = threadIdx.x;
    const int c    = tid & 255;      // col id: this thread's cols are c + 256*j
    const int g    = tid >> 8;       // row group 0..3
    const int lane = tid & 63;
    const int wv   = tid >> 6;       // wave 0..15

    // ---- W fragment: rows row0..row0+7, cols c+256*j — register-resident ----
    const int row0 = b * BROWS + g * GROWS;
    float w[GROWS][KCH];
    #pragma unroll
    for (int r = 0; r < GROWS; ++r) {
        const float* wp = W + (size_t)(row0 + r) * UNITS + c;
        #pragma unroll
        for (int j = 0; j < KCH; ++j) w[r][j] = wp[j * CSTR];
    }
    #pragma unroll
    for (int r = 0; r < GROWS; ++r)
        #pragma unroll
        for (int j = 0; j < KCH; ++j)
            asm volatile("" : "+v"(w[r][j]));   // opaque def: keep live in VGPRs

    float winv[GROWS];
    #pragma unroll
    for (int r = 0; r < GROWS; ++r) winv[r] = 0.f;
    if (c < IN_DIM) {
        #pragma unroll
        for (int r = 0; r < GROWS; ++r)
            winv[r] = Win[(size_t)(row0 + r) * IN_DIM + c];
    }
    #pragma unroll
    for (int r = 0; r < GROWS; ++r) asm volatile("" : "+v"(winv[r]));

    float s_old = (tid < BROWS) ? s0[b * BROWS + tid] : 0.f;

    __shared__ float sv_lds[2][UNITS];          // parity-buffered state vector
    __shared__ float red[2][16][4][GROWS];      // per-wave, per-row16 partials
    __shared__ u32 cnt_sv[2];                   // monotone poller-deposit counters
    __shared__ u32 cnt_red[2];                  // monotone wave-partial counters

    // ---- pre-loop: local deposit of s_0 (no comm needed for step 0) ----
    if (tid < 256) {
        float4 a  = *(const float4*)(s0 + tid * 8);
        float4 bb = *(const float4*)(s0 + tid * 8 + 4);
        *(float4*)&sv_lds[0][tid * 8]     = a;
        *(float4*)&sv_lds[0][tid * 8 + 4] = bb;
    }
    if (tid == 0) { cnt_sv[0] = 4u; cnt_sv[1] = 0u; cnt_red[0] = 0u; cnt_red[1] = 0u; }
    __syncthreads();   // one-time only

    for (int t = 0; t < T_STEPS; ++t) {
        const int par   = t & 1;
        const u32 epoch = (u32)(t >> 1) + 1u;

        // input drive for step t (issue before the spin to hide latency)
        float u = 0.f;
        if (c < IN_DIM) u = inp[(size_t)t * IN_DIM + c];

        // ---- wait for sv[par] = s_t (pollers spin tight; others back off) ----
        if (wv >= 4) {
            while (__hip_atomic_load(&cnt_sv[par], __ATOMIC_ACQUIRE,
                                     __HIP_MEMORY_SCOPE_WORKGROUP) < 4u * epoch)
                __builtin_amdgcn_s_sleep(1);
        } else {
            while (__hip_atomic_load(&cnt_sv[par], __ATOMIC_ACQUIRE,
                                     __HIP_MEMORY_SCOPE_WORKGROUP) < 4u * epoch) {}
        }

        // ---- operands from LDS (lane-consecutive: conflict-free) ----
        float sv[KCH];
        #pragma unroll
        for (int j = 0; j < KCH; ++j) sv[j] = sv_lds[par][c + j * CSTR];

        // ---- partial matvec: 64 FMAs ----
        float acc[GROWS];
        #pragma unroll
        for (int r = 0; r < GROWS; ++r) {
            float a = 0.f;
            #pragma unroll
            for (int k = 0; k < KCH; ++k) a = fmaf(w[r][k], sv[k], a);
            acc[r] = a;
        }
        if (c < IN_DIM) {
            #pragma unroll
            for (int r = 0; r < GROWS; ++r) acc[r] = fmaf(winv[r], u, acc[r]);
        }

        // ---- reduce across 16 lanes via VALU DPP (no LDS pipe) ----
        #pragma unroll
        for (int r = 0; r < GROWS; ++r) {
            acc[r] = dpp_add<0xB1>(acc[r]);    // quad_perm xor1
            acc[r] = dpp_add<0x4E>(acc[r]);    // quad_perm xor2
            acc[r] = dpp_add<0x141>(acc[r]);   // row_half_mirror (+other quad)
            acc[r] = dpp_add<0x140>(acc[r]);   // row_mirror (+other 8)
        }
        if ((lane & 15) < 8) {
            float v = acc[0];                  // static select acc[lane&7]
            #pragma unroll
            for (int r = 1; r < GROWS; ++r) v = ((lane & 7) == r) ? acc[r] : v;
            red[par][wv][lane >> 4][lane & 7] = v;
        }
        if (lane == 0)
            __hip_atomic_fetch_add(&cnt_red[par], 1u, __ATOMIC_RELEASE,
                                   __HIP_MEMORY_SCOPE_WORKGROUP);

        // ---- finalize: 32 threads combine 16 partials, publish immediately ----
        if (tid < BROWS) {
            while (__hip_atomic_load(&cnt_red[par], __ATOMIC_ACQUIRE,
                                     __HIP_MEMORY_SCOPE_WORKGROUP) < 16u * epoch) {}
            const int gg = tid >> 3, rr = tid & 7;
            float pre = 0.f;
            #pragma unroll
            for (int q = 0; q < 4; ++q)
                #pragma unroll
                for (int h = 0; h < 4; ++h)
                    pre += red[par][4 * gg + q][h][rr];
            float e  = __expf(2.0f * pre);
            float th = 1.0f - 2.0f / (e + 1.0f);
            float sn = 0.9f * s_old + 0.1f * th;
            s_old = sn;
            const int j = b * BROWS + tid;
            out[(size_t)t * UNITS + j] = sn;
            if (t == T_STEPS - 1) {
                out[(size_t)T_STEPS * UNITS + j] = sn;
            } else {
                u32x2 vt; vt[0] = __float_as_uint(sn); vt[1] = (u32)(t + 1);
                u32x2* ps = buf + ((t + 1) & 1) * UNITS + j;
                asm volatile("global_store_dwordx2 %0, %1, off sc0 sc1"
                             :: "v"(ps), "v"(vt) : "memory");
            }
        }

        // ---- pollers gather s_{t+1} for the next iteration (direct 64B poll) ----
        if (wv < 4 && t < T_STEPS - 1) {
            const int pnx = (t + 1) & 1;
            const u32 tag = (u32)(t + 1);
            const u32x2* pp = buf + pnx * UNITS + tid * KCH;
            u32x4 A, B, C, D;
            while (true) {
                asm volatile(
                    "global_load_dwordx4 %0, %4, off sc0 sc1\n\t"
                    "global_load_dwordx4 %1, %4, off offset:16 sc0 sc1\n\t"
                    "global_load_dwordx4 %2, %4, off offset:32 sc0 sc1\n\t"
                    "global_load_dwordx4 %3, %4, off offset:48 sc0 sc1\n\t"
                    "s_waitcnt vmcnt(0)"
                    : "=v"(A), "=v"(B), "=v"(C), "=v"(D)
                    : "v"(pp)
                    : "memory");
                bool ok = (A[1] == tag) & (A[3] == tag) & (B[1] == tag) & (B[3] == tag)
                        & (C[1] == tag) & (C[3] == tag) & (D[1] == tag) & (D[3] == tag);
                if (ok) break;
            }
            float4 v0, v1;
            v0.x = __uint_as_float(A[0]); v0.y = __uint_as_float(A[2]);
            v0.z = __uint_as_float(B[0]); v0.w = __uint_as_float(B[2]);
            v1.x = __uint_as_float(C[0]); v1.y = __uint_as_float(C[2]);
            v1.z = __uint_as_float(D[0]); v1.w = __uint_as_float(D[2]);
            float4* dst = (float4*)&sv_lds[pnx][tid * KCH];
            dst[0] = v0; dst[1] = v1;
            if (lane == 0)
                __hip_atomic_fetch_add(&cnt_sv[pnx], 1u, __ATOMIC_RELEASE,
                                       __HIP_MEMORY_SCOPE_WORKGROUP);
        }
    }
}

extern "C" void kernel_launch(void* const* d_in, const int* in_sizes, int n_in,
                              void* d_out, int out_size, void* d_ws, size_t ws_size,
                              hipStream_t stream) {
    const float* inp = (const float*)d_in[0];   // input_sequence [4096,128]
    const float* s0  = (const float*)d_in[1];   // initial_state  [1,2048]
    const float* W   = (const float*)d_in[2];   // W   [2048,2048]
    const float* Win = (const float*)d_in[3];   // Win [2048,128]
    float* out = (float*)d_out;
    u32x2* buf = (u32x2*)d_ws;                  // 2*2048*8 = 32 KiB scratch

    esn_init<<<dim3(16), dim3(256), 0, stream>>>(buf);

    void* args[6];
    args[0] = (void*)&inp; args[1] = (void*)&s0;  args[2] = (void*)&W;
    args[3] = (void*)&Win; args[4] = (void*)&out; args[5] = (void*)&buf;
    hipLaunchCooperativeKernel((void*)esn_step, dim3(NBLK), dim3(TPB), args, 0, stream);
}